// Round 1
// baseline (756.241 us; speedup 1.0000x reference)
//
#include <hip/hip_runtime.h>

#define NN 100000
#define NE 1000000
#define NG 2048
#define HD 64

// ---------------- graph preprocessing ----------------

__global__ void k_deg(const int* __restrict__ dst, int* __restrict__ cnt, int E) {
    int i = blockIdx.x * blockDim.x + threadIdx.x;
    if (i < E) atomicAdd(&cnt[dst[i]], 1);
}

__global__ void k_scan(const int* __restrict__ cnt, int* __restrict__ row_ptr, int n) {
    __shared__ int buf[1024];
    int tid = threadIdx.x;
    int chunk = (n + 1023) >> 10;
    int start = tid * chunk;
    int end = min(start + chunk, n);
    int s = 0;
    for (int i = start; i < end; ++i) s += cnt[i];
    buf[tid] = s;
    __syncthreads();
    for (int off = 1; off < 1024; off <<= 1) {
        int v = (tid >= off) ? buf[tid - off] : 0;
        __syncthreads();
        buf[tid] += v;
        __syncthreads();
    }
    int run = buf[tid] - s;  // exclusive prefix
    for (int i = start; i < end; ++i) { row_ptr[i] = run; run += cnt[i]; }
    if (tid == 1023) row_ptr[n] = buf[1023];
}

__global__ void k_dinv(const int* __restrict__ cnt, float* __restrict__ dinv,
                       float* __restrict__ invd, int n) {
    int i = blockIdx.x * blockDim.x + threadIdx.x;
    if (i < n) {
        float d = (float)(cnt[i] + 1);  // self-loop
        dinv[i] = rsqrtf(d);
        invd[i] = 1.0f / d;
    }
}

__global__ void k_fill(const int* __restrict__ src, const int* __restrict__ dst,
                       const int* __restrict__ row_ptr, int* __restrict__ fill,
                       int* __restrict__ csr_src, int E) {
    int i = blockIdx.x * blockDim.x + threadIdx.x;
    if (i < E) {
        int d = dst[i];
        int pos = row_ptr[d] + atomicAdd(&fill[d], 1);
        csr_src[pos] = src[i];
    }
}

// ---------------- dense matmuls ----------------

__global__ void k_mm1(const float* __restrict__ x, const float* __restrict__ W,
                      float* __restrict__ out, int n) {
    __shared__ float Ws[9 * 64];
    int tid = threadIdx.x;
    for (int i = tid; i < 9 * 64; i += 256) Ws[i] = W[i];
    __syncthreads();
    int node = blockIdx.x * 4 + (tid >> 6);
    int f = tid & 63;
    if (node < n) {
        float acc = 0.f;
        #pragma unroll
        for (int k = 0; k < 9; ++k) acc += x[node * 9 + k] * Ws[k * 64 + f];
        out[node * 64 + f] = acc;
    }
}

__global__ void k_mm64(const float* __restrict__ h, const float* __restrict__ W,
                       float* __restrict__ out, int n) {
    __shared__ float Ws[64 * 64];
    __shared__ float xs[4][64];
    int tid = threadIdx.x;
    for (int i = tid; i < 4096; i += 256) Ws[i] = W[i];
    int li = tid >> 6;
    int f = tid & 63;
    int node = blockIdx.x * 4 + li;
    if (node < n) xs[li][f] = h[node * 64 + f];
    __syncthreads();
    if (node < n) {
        float acc = 0.f;
        #pragma unroll
        for (int k = 0; k < 64; ++k) acc += xs[li][k] * Ws[k * 64 + f];
        out[node * 64 + f] = acc;
    }
}

// ---------------- CSR aggregation (+ self loop + bias + relu) ----------------

__global__ void k_agg(const float* __restrict__ hlin, float* __restrict__ hout,
                      const int* __restrict__ csr_src, const int* __restrict__ row_ptr,
                      const float* __restrict__ dinv, const float* __restrict__ invd,
                      const float* __restrict__ bias, int n) {
    int tid = threadIdx.x;
    int node = blockIdx.x * 4 + (tid >> 6);
    int f = tid & 63;
    if (node >= n) return;
    int beg = row_ptr[node], endp = row_ptr[node + 1];
    float acc = 0.f;
    for (int e = beg; e < endp; ++e) {
        int s = csr_src[e];
        acc += hlin[s * 64 + f] * dinv[s];
    }
    float v = acc * dinv[node] + hlin[node * 64 + f] * invd[node] + bias[f];
    hout[node * 64 + f] = fmaxf(v, 0.f);
}

// ---------------- pooling ----------------

__global__ void k_count(const int* __restrict__ batch, int* __restrict__ pcnt, int n) {
    int i = blockIdx.x * blockDim.x + threadIdx.x;
    if (i < n) atomicAdd(&pcnt[batch[i]], 1);
}

__global__ void k_pool(const float* __restrict__ h, const int* __restrict__ batch,
                       float* __restrict__ psum, float* __restrict__ pmax, int n) {
    int idx = blockIdx.x * blockDim.x + threadIdx.x;
    int node = idx >> 6;
    int f = idx & 63;
    if (node >= n) return;
    float v = h[node * 64 + f];
    int g = batch[node];
    atomicAdd(&psum[g * 64 + f], v);
    atomicMax((int*)&pmax[g * 64 + f], __float_as_int(v));  // v >= 0 after relu
}

// ---------------- predictor MLP ----------------

__global__ void k_pred(const float* __restrict__ psum, const float* __restrict__ pmax,
                       const int* __restrict__ pcnt,
                       const float* __restrict__ Wp1, const float* __restrict__ bp1,
                       const float* __restrict__ Wp2, const float* __restrict__ bp2,
                       float* __restrict__ out, int G) {
    __shared__ float gs[4][128];
    int tid = threadIdx.x;
    int li = tid >> 6;
    int lane = tid & 63;
    int gi = blockIdx.x * 4 + li;
    if (gi < G) {
        float c = fmaxf((float)pcnt[gi], 1.0f);
        gs[li][lane] = psum[gi * 64 + lane] / c;
        gs[li][64 + lane] = pmax[gi * 64 + lane];
    }
    __syncthreads();
    if (gi >= G) return;
    float acc = bp1[lane];
    #pragma unroll
    for (int k = 0; k < 128; ++k) acc += gs[li][k] * Wp1[k * 64 + lane];
    acc = fmaxf(acc, 0.f);
    float r = acc * Wp2[lane];
    #pragma unroll
    for (int off = 32; off; off >>= 1) r += __shfl_down(r, off, 64);
    if (lane == 0) out[gi] = r + bp2[0];
}

// ---------------- launch ----------------

extern "C" void kernel_launch(void* const* d_in, const int* in_sizes, int n_in,
                              void* d_out, int out_size, void* d_ws, size_t ws_size,
                              hipStream_t stream) {
    const float* x    = (const float*)d_in[0];
    const int*   esrc = (const int*)d_in[1];
    const int*   edst = (const int*)d_in[2];
    const int*   batch= (const int*)d_in[3];
    const float* W1 = (const float*)d_in[4];  const float* b1 = (const float*)d_in[5];
    const float* W2 = (const float*)d_in[6];  const float* b2 = (const float*)d_in[7];
    const float* W3 = (const float*)d_in[8];  const float* b3 = (const float*)d_in[9];
    const float* Wp1= (const float*)d_in[10]; const float* bp1= (const float*)d_in[11];
    const float* Wp2= (const float*)d_in[12]; const float* bp2= (const float*)d_in[13];
    float* out = (float*)d_out;

    char* ws = (char*)d_ws;
    // zero-init region (contiguous): [cnt][fill][psum][pmax][pcnt]
    int*   cnt     = (int*)  (ws + 0);          // N ints
    int*   fill    = (int*)  (ws + 400000);     // N ints
    float* psum    = (float*)(ws + 800000);     // G*64 floats
    float* pmax    = (float*)(ws + 1324288);    // G*64 floats
    int*   pcnt    = (int*)  (ws + 1848576);    // G ints
    const size_t ZBYTES = 1856768;
    float* dinv    = (float*)(ws + 1856768);    // N floats
    float* invd    = (float*)(ws + 2256768);    // N floats
    int*   row_ptr = (int*)  (ws + 2656768);    // N+1 ints (padded)
    int*   csr_src = (int*)  (ws + 3056896);    // E ints
    float* hA      = (float*)(ws + 7056896);    // N*64 floats
    float* hB      = (float*)(ws + 32656896);   // N*64 floats

    hipMemsetAsync(ws, 0, ZBYTES, stream);

    k_deg <<<(NE + 255) / 256, 256, 0, stream>>>(edst, cnt, NE);
    k_scan<<<1, 1024, 0, stream>>>(cnt, row_ptr, NN);
    k_dinv<<<(NN + 255) / 256, 256, 0, stream>>>(cnt, dinv, invd, NN);
    k_fill<<<(NE + 255) / 256, 256, 0, stream>>>(esrc, edst, row_ptr, fill, csr_src, NE);

    int nb4 = (NN + 3) / 4;
    k_mm1 <<<nb4, 256, 0, stream>>>(x, W1, hA, NN);
    k_agg <<<nb4, 256, 0, stream>>>(hA, hB, csr_src, row_ptr, dinv, invd, b1, NN);
    k_mm64<<<nb4, 256, 0, stream>>>(hB, W2, hA, NN);
    k_agg <<<nb4, 256, 0, stream>>>(hA, hB, csr_src, row_ptr, dinv, invd, b2, NN);
    k_mm64<<<nb4, 256, 0, stream>>>(hB, W3, hA, NN);
    k_agg <<<nb4, 256, 0, stream>>>(hA, hB, csr_src, row_ptr, dinv, invd, b3, NN);

    k_count<<<(NN + 255) / 256, 256, 0, stream>>>(batch, pcnt, NN);
    k_pool <<<(NN * 64 + 255) / 256, 256, 0, stream>>>(hB, batch, psum, pmax, NN);
    k_pred <<<(NG + 3) / 4, 256, 0, stream>>>(psum, pmax, pcnt, Wp1, bp1, Wp2, bp2, out, NG);
}